// Round 4
// baseline (340.815 us; speedup 1.0000x reference)
//
#include <hip/hip_runtime.h>
#include <math.h>

#define KC 16
#define DF 256

// ws layout
#define WS_POOLED 0          // [16*256] S^T F accumulator (floats)
#define WS_CS     4096       // [16] cluster sizes
#define WS_M      4112       // [16] m_k = sum_e val*S[row][k]
#define WS_TR     4128       // trace accumulator
#define WS_ESUM   4129       // sum of edge_val (= 2*n_edges)
#define WS_TOTAL  4130
#define S8_OFF_BYTES 16640   // fp8 S shadow copy, 16 B/row

typedef float v2f  __attribute__((ext_vector_type(2)));
typedef unsigned int u32x4 __attribute__((ext_vector_type(4)));

__global__ void zero_ws_kernel(float* __restrict__ ws) {
  int i = blockIdx.x * blockDim.x + threadIdx.x;
  if (i < WS_TOTAL) ws[i] = 0.0f;
}

__device__ __forceinline__ unsigned pk4_fp8(float a, float b, float c, float d) {
  unsigned w = (unsigned)__builtin_amdgcn_cvt_pk_fp8_f32(a, b, 0, false);
  w = (unsigned)__builtin_amdgcn_cvt_pk_fp8_f32(c, d, (int)w, true);
  return w;
}
__device__ __forceinline__ void cvt4_fp8(unsigned w, float* f) {
  v2f p = __builtin_amdgcn_cvt_pk_f32_fp8(w, false);
  f[0] = p.x; f[1] = p.y;
  p = __builtin_amdgcn_cvt_pk_f32_fp8(w, true);
  f[2] = p.x; f[3] = p.y;
}
__device__ __forceinline__ void cvt16_fp8(u32x4 u, float* f) {
  cvt4_fp8(u.x, f); cvt4_fp8(u.y, f + 4);
  cvt4_fp8(u.z, f + 8); cvt4_fp8(u.w, f + 12);
}

// ---------------------------------------------------------------------------
// assignments = softmax(F @ W + b) + cluster sizes + fp8 shadow of S.
// Thread-per-node; F staged transposed in LDS (stride 257); register
// double-buffer prefetch hides global latency. W/b via scalar loads.
// ---------------------------------------------------------------------------
__global__ void __launch_bounds__(256) assign_kernel(
    const float* __restrict__ F, const float* __restrict__ W,
    const float* __restrict__ b, float* __restrict__ S,
    unsigned* __restrict__ S8, float* __restrict__ ws, int n) {
  __shared__ float Ft[32 * 257];
  __shared__ float cs_l[KC];
  const int t = threadIdx.x;
  if (t < KC) cs_l[t] = 0.0f;
  const int nb = blockIdx.x << 8;
  const int node = nb + t;
  const bool valid = node < n;
  const bool interior = (nb + 256 <= n);

  const int nl = t >> 3;
  const int jc = t & 7;

  float4 pref[8];
  auto load_chunk = [&](int s) {
    #pragma unroll
    for (int it = 0; it < 8; ++it) {
      const int nn = nl + (it << 5);
      if (interior || nb + nn < n)
        pref[it] = *(const float4*)&F[(size_t)(nb + nn) * DF + (s << 5) + (jc << 2)];
      else
        pref[it] = make_float4(0.f, 0.f, 0.f, 0.f);
    }
  };

  float acc[KC];
  #pragma unroll
  for (int k = 0; k < KC; ++k) acc[k] = 0.f;

  load_chunk(0);
  for (int s = 0; s < 8; ++s) {
    __syncthreads();
    #pragma unroll
    for (int it = 0; it < 8; ++it) {
      const int nn = nl + (it << 5);
      const int d0 = jc << 2;
      Ft[(d0 + 0) * 257 + nn] = pref[it].x;
      Ft[(d0 + 1) * 257 + nn] = pref[it].y;
      Ft[(d0 + 2) * 257 + nn] = pref[it].z;
      Ft[(d0 + 3) * 257 + nn] = pref[it].w;
    }
    __syncthreads();
    if (s < 7) load_chunk(s + 1);
    #pragma unroll
    for (int j = 0; j < 8; ++j) {
      const float fv0 = Ft[(4 * j + 0) * 257 + t];
      const float fv1 = Ft[(4 * j + 1) * 257 + t];
      const float fv2 = Ft[(4 * j + 2) * 257 + t];
      const float fv3 = Ft[(4 * j + 3) * 257 + t];
      const float* __restrict__ Wg = &W[(size_t)((s << 5) + (j << 2)) * KC];
      #pragma unroll
      for (int k = 0; k < KC; ++k)
        acc[k] += fv0 * Wg[k] + fv1 * Wg[KC + k]
                + fv2 * Wg[2 * KC + k] + fv3 * Wg[3 * KC + k];
    }
  }

  float mx = -1e30f;
  #pragma unroll
  for (int k = 0; k < KC; ++k) { acc[k] += b[k]; mx = fmaxf(mx, acc[k]); }
  float sum = 0.f;
  #pragma unroll
  for (int k = 0; k < KC; ++k) { acc[k] = __expf(acc[k] - mx); sum += acc[k]; }
  const float inv = 1.0f / sum;
  #pragma unroll
  for (int k = 0; k < KC; ++k) acc[k] *= inv;
  if (!valid) {
    #pragma unroll
    for (int k = 0; k < KC; ++k) acc[k] = 0.f;
  }
  if (valid) {
    float4* __restrict__ So = (float4*)&S[(size_t)node * KC];
    So[0] = make_float4(acc[0],  acc[1],  acc[2],  acc[3]);
    So[1] = make_float4(acc[4],  acc[5],  acc[6],  acc[7]);
    So[2] = make_float4(acc[8],  acc[9],  acc[10], acc[11]);
    So[3] = make_float4(acc[12], acc[13], acc[14], acc[15]);
    if (S8) {
      u32x4 p;
      p.x = pk4_fp8(acc[0],  acc[1],  acc[2],  acc[3]);
      p.y = pk4_fp8(acc[4],  acc[5],  acc[6],  acc[7]);
      p.z = pk4_fp8(acc[8],  acc[9],  acc[10], acc[11]);
      p.w = pk4_fp8(acc[12], acc[13], acc[14], acc[15]);
      *(u32x4*)&S8[(size_t)node * 4] = p;
    }
  }
  #pragma unroll
  for (int off = 1; off < 64; off <<= 1) {
    #pragma unroll
    for (int k = 0; k < KC; ++k) acc[k] += __shfl_xor(acc[k], off);
  }
  if ((t & 63) == 0) {
    #pragma unroll
    for (int k = 0; k < KC; ++k) atomicAdd(&cs_l[k], acc[k]);
  }
  __syncthreads();
  if (t < KC) atomicAdd(&ws[WS_CS + t], cs_l[t]);
}

// ---------------------------------------------------------------------------
// Edge pass (fp8 S, one 16B gather per row): 4 edges/iter, all loads issued
// before any FMA; nontemporal (L1-bypass) loads.
// ---------------------------------------------------------------------------
__device__ __forceinline__ void acc_edge8(u32x4 ar, u32x4 ac, float v,
                                          float* m, float& tr, float& es) {
  float a[16], bb[16];
  cvt16_fp8(ar, a);
  cvt16_fp8(ac, bb);
  float d = 0.f;
  #pragma unroll
  for (int k = 0; k < 16; ++k) d += a[k] * bb[k];
  tr += v * d;
  es += v;
  #pragma unroll
  for (int k = 0; k < 16; ++k) m[k] += v * a[k];
}

__global__ void __launch_bounds__(256) edge_kernel_fp8(
    const int* __restrict__ erow, const int* __restrict__ ecol,
    const float* __restrict__ evl, const u32x4* __restrict__ S8,
    float* __restrict__ ws, int ne) {
  __shared__ float red[KC + 2];
  const int t = threadIdx.x;
  if (t < KC + 2) red[t] = 0.0f;
  __syncthreads();

  float m[KC];
  #pragma unroll
  for (int i = 0; i < KC; ++i) m[i] = 0.f;
  float tr = 0.f, es = 0.f;

  const int tid = blockIdx.x * 256 + t;
  const int stride = gridDim.x * 256;
  for (int e0 = tid; e0 < ne; e0 += 4 * stride) {
    const int eB = e0 + stride, eC = e0 + 2 * stride, eD = e0 + 3 * stride;
    int rA = __builtin_nontemporal_load(&erow[e0]);
    int cA = __builtin_nontemporal_load(&ecol[e0]);
    float vA = __builtin_nontemporal_load(&evl[e0]);
    int rB = 0, cB = 0, rC = 0, cC = 0, rD = 0, cD = 0;
    float vB = 0.f, vC = 0.f, vD = 0.f;
    if (eB < ne) { rB = __builtin_nontemporal_load(&erow[eB]);
                   cB = __builtin_nontemporal_load(&ecol[eB]);
                   vB = __builtin_nontemporal_load(&evl[eB]); }
    if (eC < ne) { rC = __builtin_nontemporal_load(&erow[eC]);
                   cC = __builtin_nontemporal_load(&ecol[eC]);
                   vC = __builtin_nontemporal_load(&evl[eC]); }
    if (eD < ne) { rD = __builtin_nontemporal_load(&erow[eD]);
                   cD = __builtin_nontemporal_load(&ecol[eD]);
                   vD = __builtin_nontemporal_load(&evl[eD]); }
    // issue all 8 gathers before any compute
    const u32x4 aA = __builtin_nontemporal_load(&S8[rA]);
    const u32x4 bA = __builtin_nontemporal_load(&S8[cA]);
    const u32x4 aB = __builtin_nontemporal_load(&S8[rB]);
    const u32x4 bB = __builtin_nontemporal_load(&S8[cB]);
    const u32x4 aC = __builtin_nontemporal_load(&S8[rC]);
    const u32x4 bC = __builtin_nontemporal_load(&S8[cC]);
    const u32x4 aD = __builtin_nontemporal_load(&S8[rD]);
    const u32x4 bD = __builtin_nontemporal_load(&S8[cD]);
    acc_edge8(aA, bA, vA, m, tr, es);
    acc_edge8(aB, bB, vB, m, tr, es);
    acc_edge8(aC, bC, vC, m, tr, es);
    acc_edge8(aD, bD, vD, m, tr, es);
  }
  #pragma unroll
  for (int off = 1; off < 64; off <<= 1) {
    tr += __shfl_xor(tr, off);
    es += __shfl_xor(es, off);
    #pragma unroll
    for (int i = 0; i < KC; ++i) m[i] += __shfl_xor(m[i], off);
  }
  if ((t & 63) == 0) {
    atomicAdd(&red[KC], tr);
    atomicAdd(&red[KC + 1], es);
    #pragma unroll
    for (int i = 0; i < KC; ++i) atomicAdd(&red[i], m[i]);
  }
  __syncthreads();
  if (t < KC)            atomicAdd(&ws[WS_M + t], red[t]);
  else if (t == KC)      atomicAdd(&ws[WS_TR], red[KC]);
  else if (t == KC + 1)  atomicAdd(&ws[WS_ESUM], red[KC + 1]);
}

// fp32 fallback (ws too small for the fp8 shadow)
__global__ void __launch_bounds__(256) edge_kernel_f32(
    const int* __restrict__ erow, const int* __restrict__ ecol,
    const float* __restrict__ evl, const float* __restrict__ S,
    float* __restrict__ ws, int ne) {
  __shared__ float red[KC + 2];
  const int t = threadIdx.x;
  if (t < KC + 2) red[t] = 0.0f;
  __syncthreads();
  float m[KC];
  #pragma unroll
  for (int i = 0; i < KC; ++i) m[i] = 0.f;
  float tr = 0.f, es = 0.f;
  const int stride = gridDim.x * blockDim.x;
  for (int e = blockIdx.x * blockDim.x + t; e < ne; e += stride) {
    const int r = erow[e];
    const int c = ecol[e];
    const float v = evl[e];
    const float4* __restrict__ Sr = (const float4*)(S + (size_t)r * KC);
    const float4* __restrict__ Sc = (const float4*)(S + (size_t)c * KC);
    const float4 a0 = Sr[0], a1 = Sr[1], a2 = Sr[2], a3 = Sr[3];
    const float4 b0 = Sc[0], b1 = Sc[1], b2 = Sc[2], b3 = Sc[3];
    float d = a0.x*b0.x + a0.y*b0.y + a0.z*b0.z + a0.w*b0.w
            + a1.x*b1.x + a1.y*b1.y + a1.z*b1.z + a1.w*b1.w
            + a2.x*b2.x + a2.y*b2.y + a2.z*b2.z + a2.w*b2.w
            + a3.x*b3.x + a3.y*b3.y + a3.z*b3.z + a3.w*b3.w;
    tr += v * d; es += v;
    m[0]+=v*a0.x; m[1]+=v*a0.y; m[2]+=v*a0.z; m[3]+=v*a0.w;
    m[4]+=v*a1.x; m[5]+=v*a1.y; m[6]+=v*a1.z; m[7]+=v*a1.w;
    m[8]+=v*a2.x; m[9]+=v*a2.y; m[10]+=v*a2.z; m[11]+=v*a2.w;
    m[12]+=v*a3.x; m[13]+=v*a3.y; m[14]+=v*a3.z; m[15]+=v*a3.w;
  }
  #pragma unroll
  for (int off = 1; off < 64; off <<= 1) {
    tr += __shfl_xor(tr, off);
    es += __shfl_xor(es, off);
    #pragma unroll
    for (int i = 0; i < KC; ++i) m[i] += __shfl_xor(m[i], off);
  }
  if ((t & 63) == 0) {
    atomicAdd(&red[KC], tr);
    atomicAdd(&red[KC + 1], es);
    #pragma unroll
    for (int i = 0; i < KC; ++i) atomicAdd(&red[i], m[i]);
  }
  __syncthreads();
  if (t < KC)            atomicAdd(&ws[WS_M + t], red[t]);
  else if (t == KC)      atomicAdd(&ws[WS_TR], red[KC]);
  else if (t == KC + 1)  atomicAdd(&ws[WS_ESUM], red[KC + 1]);
}

// ---------------------------------------------------------------------------
// pooled = S^T @ F. Thread owns feature column t; 32 register-staged F loads
// per chunk before the FMA block; S rows are uniform -> scalar loads.
// ---------------------------------------------------------------------------
__global__ void __launch_bounds__(256) pool_kernel(
    const float* __restrict__ F, const float* __restrict__ S,
    float* __restrict__ ws, int n) {
  const int t = threadIdx.x;
  float acc[KC];
  #pragma unroll
  for (int i = 0; i < KC; ++i) acc[i] = 0.f;

  const int nch = n >> 5;
  for (int ch = blockIdx.x; ch < nch; ch += gridDim.x) {
    const int base = ch << 5;
    float fl[32];
    #pragma unroll
    for (int i = 0; i < 32; ++i)
      fl[i] = F[(size_t)(base + i) * DF + t];
    #pragma unroll
    for (int i = 0; i < 32; ++i) {
      const float4* __restrict__ Sr = (const float4*)(S + (size_t)(base + i) * KC);
      const float4 s0 = Sr[0], s1 = Sr[1], s2 = Sr[2], s3 = Sr[3];
      const float f = fl[i];
      acc[0]+=f*s0.x;  acc[1]+=f*s0.y;  acc[2]+=f*s0.z;  acc[3]+=f*s0.w;
      acc[4]+=f*s1.x;  acc[5]+=f*s1.y;  acc[6]+=f*s1.z;  acc[7]+=f*s1.w;
      acc[8]+=f*s2.x;  acc[9]+=f*s2.y;  acc[10]+=f*s2.z; acc[11]+=f*s2.w;
      acc[12]+=f*s3.x; acc[13]+=f*s3.y; acc[14]+=f*s3.z; acc[15]+=f*s3.w;
    }
  }
  if (blockIdx.x == 0) {
    for (int i2 = nch << 5; i2 < n; ++i2) {
      const float f = F[(size_t)i2 * DF + t];
      const float* __restrict__ Sr = S + (size_t)i2 * KC;
      #pragma unroll
      for (int kk = 0; kk < KC; ++kk) acc[kk] += f * Sr[kk];
    }
  }
  #pragma unroll
  for (int kk = 0; kk < KC; ++kk)
    atomicAdd(&ws[WS_POOLED + kk * DF + t], acc[kk]);
}

__global__ void finalize_kernel(const float* __restrict__ ws,
                                float* __restrict__ out, int n) {
  const int t = threadIdx.x;
  const float alpha = 1.6732632423543772f;
  const float scale = 1.0507009873554805f;
  for (int idx = t; idx < KC * DF; idx += blockDim.x) {
    const int k = idx >> 8;
    const float x = ws[WS_POOLED + idx] / ws[WS_CS + k];
    const float r = x > 0.f ? x : alpha * expm1f(x);
    out[idx] = scale * r;
  }
  if (t == 0) {
    const float esum = ws[WS_ESUM];   // = 2 * n_edges
    const float tr = ws[WS_TR];
    float sm2 = 0.f, sc2 = 0.f;
    for (int i = 0; i < KC; ++i) {
      const float mi = ws[WS_M + i];
      sm2 += mi * mi;
      const float ci = ws[WS_CS + i];
      sc2 += ci * ci;
    }
    const float spectral = -(tr - sm2 / esum) / esum;
    const float collapse = 0.1f * (sqrtf(sc2) / (float)n * 4.0f - 1.0f);
    const size_t off = (size_t)(KC * DF) + (size_t)n * KC;
    out[off] = spectral;
    out[off + 1] = collapse;
  }
}

extern "C" void kernel_launch(void* const* d_in, const int* in_sizes, int n_in,
                              void* d_out, int out_size, void* d_ws, size_t ws_size,
                              hipStream_t stream) {
  const float* F   = (const float*)d_in[0];
  const float* W   = (const float*)d_in[1];
  const float* b   = (const float*)d_in[2];
  const int* erow  = (const int*)d_in[3];
  const int* ecol  = (const int*)d_in[4];
  const float* evl = (const float*)d_in[5];
  const int n  = in_sizes[0] / DF;
  const int ne = in_sizes[3];
  float* out = (float*)d_out;
  float* S   = out + KC * DF;      // assignments live directly in d_out
  float* ws  = (float*)d_ws;

  const bool use_fp8 = ws_size >= (size_t)S8_OFF_BYTES + (size_t)n * 16 + 64;
  unsigned* S8 = use_fp8 ? (unsigned*)((char*)d_ws + S8_OFF_BYTES) : nullptr;

  zero_ws_kernel<<<(WS_TOTAL + 255) / 256, 256, 0, stream>>>(ws);
  assign_kernel<<<(n + 255) / 256, 256, 0, stream>>>(F, W, b, S, S8, ws, n);
  if (use_fp8)
    edge_kernel_fp8<<<2048, 256, 0, stream>>>(erow, ecol, evl, (const u32x4*)S8, ws, ne);
  else
    edge_kernel_f32<<<2048, 256, 0, stream>>>(erow, ecol, evl, S, ws, ne);
  pool_kernel<<<1024, 256, 0, stream>>>(F, S, ws, n);
  finalize_kernel<<<1, 256, 0, stream>>>(ws, out, n);
}